// Round 4
// baseline (196.217 us; speedup 1.0000x reference)
//
#include <hip/hip_runtime.h>
#include <hip/hip_bf16.h>

// ---------------------------------------------------------------------------
// MappingNetwork: backbone 4x(Linear+ReLU) [16->128, 3x 128->128], then the
// selected expert head only (4 layers, last no-ReLU, 128->64).
//
// Round-4 structure: BARRIER-FREE. One wave (64 threads = 1 block) owns 64
// samples end-to-end. After the up-front B-fragment loads (af[2][8]) the
// wave's whole 64x128 activation tile is register-resident; the private LDS
// slice is only the C-layout -> B-layout relayout buffer. No __syncthreads
// on the hot path; cross-phase ordering is in-wave lgkmcnt (compiler).
//
// Numerics (validated r3, absmax 1.5e-5): MFMA f32_32x32x16_f16, acts f16,
// W exact via 2-term split w = whi + (wlo*1024)/1024 in separate accs.
// Operand swap mfma(Wfrag, ActFrag, acc): D col = sample, D regs = feature.
// ---------------------------------------------------------------------------

typedef _Float16 f16;
typedef __attribute__((ext_vector_type(4)))  _Float16 f16x4;
typedef __attribute__((ext_vector_type(8)))  _Float16 f16x8;
typedef __attribute__((ext_vector_type(16))) float    f32x16;

#define MFMA(a, b, c) __builtin_amdgcn_mfma_f32_32x32x16_f16((a), (b), (c), 0, 0, 0)

constexpr int Bc = 65536;
constexpr int Kc = 16;     // experts
constexpr int Hc = 128;
constexpr int Dc = 64;

constexpr int PADK = 136;            // f16 row stride (68 words -> 4-way max)
constexpr int CAP  = 4608;           // slots/expert = mean 4096 + 8.3 sigma
constexpr int WPE  = CAP / 64;       // 72 head waves per expert
constexpr int NBLK = Kc * WPE;       // 1152 one-wave blocks

constexpr float INV_LOSCALE = 1.0f / 1024.0f;

constexpr int BBW_F16 = 2048 + 3 * 16384;   // backbone weights (f16 elems)
constexpr int HWE_F16 = 3 * 16384 + 8192;   // per-expert head weights

__device__ __forceinline__ f32x16 zero16() {
    f32x16 z;
#pragma unroll
    for (int i = 0; i < 16; ++i) z[i] = 0.0f;
    return z;
}

// ---------------------------------------------------------------------------
// One Linear(+ReLU) layer, 64 samples, single wave, no barriers.
// ACT: private LDS [64][PADK] f16. Wt layout [n][KD] k-fast.
// Loads the full act tile into regs (af), then per n-tile: stream W (hi+lo),
// MFMA, combine + bias (+ReLU), write f16 back to ACT.
// ---------------------------------------------------------------------------
template<int KSTEPS, bool RELU>
__device__ __forceinline__ void layer64(
    const f16* __restrict__ WHi, const f16* __restrict__ WLo,
    const float* __restrict__ bias, f16* ACT, int lane)
{
    constexpr int KD = KSTEPS * 16;
    const int l31 = lane & 31, bh = lane >> 5;

    f16x8 af[2][KSTEPS];
#pragma unroll
    for (int mt = 0; mt < 2; ++mt)
#pragma unroll
        for (int ks = 0; ks < KSTEPS; ++ks)
            af[mt][ks] = *(const f16x8*)(ACT + (32 * mt + l31) * PADK + ks * 16 + 8 * bh);

    for (int nt = 0; nt < 4; ++nt) {
        f16x8 whi[KSTEPS], wlo[KSTEPS];
        const f16* wp = WHi + (size_t)(32 * nt + l31) * KD + 8 * bh;
        const f16* wq = WLo + (size_t)(32 * nt + l31) * KD + 8 * bh;
#pragma unroll
        for (int ks = 0; ks < KSTEPS; ++ks) {
            whi[ks] = *(const f16x8*)(wp + ks * 16);
            wlo[ks] = *(const f16x8*)(wq + ks * 16);
        }

        f32x16 aH[2], aL[2];
#pragma unroll
        for (int mt = 0; mt < 2; ++mt) { aH[mt] = zero16(); aL[mt] = zero16(); }

#pragma unroll
        for (int ks = 0; ks < KSTEPS; ++ks)
#pragma unroll
            for (int mt = 0; mt < 2; ++mt) {
                aH[mt] = MFMA(whi[ks], af[mt][ks], aH[mt]);
                aL[mt] = MFMA(wlo[ks], af[mt][ks], aL[mt]);
            }

#pragma unroll
        for (int mt = 0; mt < 2; ++mt)
#pragma unroll
            for (int rg = 0; rg < 4; ++rg) {
                const int nb = 32 * nt + 8 * rg + 4 * bh;
                const float4 bv = *(const float4*)(bias + nb);
                const float bb[4] = {bv.x, bv.y, bv.z, bv.w};
                f16x4 h4;
#pragma unroll
                for (int j = 0; j < 4; ++j) {
                    float v = fmaf(aL[mt][rg * 4 + j], INV_LOSCALE,
                                   aH[mt][rg * 4 + j]) + bb[j];
                    if (RELU) v = fmaxf(v, 0.0f);
                    h4[j] = (f16)v;
                }
                *(f16x4*)(ACT + (32 * mt + l31) * PADK + nb) = h4;
            }
    }
}

// ---------------------------------------------------------------------------
// Backbone: one wave per 64 samples; z -> 4 layers -> h f16 (d_out region);
// fused per-wave expert scatter (LDS-aggregated, 1-wave block).
// ---------------------------------------------------------------------------
__global__ __launch_bounds__(64, 2) void backbone_mfma(
    const float* __restrict__ z, const int* __restrict__ y,
    const f16* __restrict__ bbH, const f16* __restrict__ bbL,
    const float* __restrict__ bb0, const float* __restrict__ bb1,
    const float* __restrict__ bb2, const float* __restrict__ bb3,
    f16* __restrict__ hHi, int* __restrict__ idxb, int* __restrict__ cursor)
{
    __shared__ f16 ACT[64 * PADK];
    __shared__ int lc[Kc];
    __shared__ int lbase[Kc];
    const int lane = threadIdx.x;
    const int s0 = blockIdx.x * 64;

    // stage z: lane -> row `lane` (16 floats -> f16)
    {
        const float* zp = z + (size_t)(s0 + lane) * 16;
        const float4 a0 = *(const float4*)(zp);
        const float4 a1 = *(const float4*)(zp + 4);
        const float4 a2 = *(const float4*)(zp + 8);
        const float4 a3 = *(const float4*)(zp + 12);
        const float zv[16] = {a0.x, a0.y, a0.z, a0.w, a1.x, a1.y, a1.z, a1.w,
                              a2.x, a2.y, a2.z, a2.w, a3.x, a3.y, a3.z, a3.w};
        f16x8 p0, p1;
#pragma unroll
        for (int j = 0; j < 8; ++j) { p0[j] = (f16)zv[j]; p1[j] = (f16)zv[8 + j]; }
        *(f16x8*)(ACT + lane * PADK)     = p0;
        *(f16x8*)(ACT + lane * PADK + 8) = p1;
    }

    layer64<1, true>(bbH,         bbL,         bb0, ACT, lane);
    layer64<8, true>(bbH + 2048,  bbL + 2048,  bb1, ACT, lane);
    layer64<8, true>(bbH + 18432, bbL + 18432, bb2, ACT, lane);
    layer64<8, true>(bbH + 34816, bbL + 34816, bb3, ACT, lane);

    // write h (f16): lane writes its own row, 256 B contiguous
#pragma unroll
    for (int j = 0; j < 16; ++j)
        *(f16x8*)(hHi + (size_t)(s0 + lane) * Hc + j * 8) =
            *(const f16x8*)(ACT + lane * PADK + j * 8);

    // fused scatter (single-wave block: __syncthreads is cheap)
    if (lane < Kc) lc[lane] = 0;
    __syncthreads();
    const int e = y[s0 + lane];
    const int r = atomicAdd(&lc[e], 1);
    __syncthreads();
    if (lane < Kc) lbase[lane] = atomicAdd(&cursor[lane], lc[lane]);
    __syncthreads();
    const int slot = lbase[e] + r;
    if (slot < CAP) idxb[e * CAP + slot] = s0 + lane;
}

// ---------------------------------------------------------------------------
// Heads: one wave per 64 samples of one expert. 3x(128->128 ReLU) +
// 128->64 (no ReLU) -> float4 direct to out[b]. No barriers anywhere.
// hHi aliases d_out (row-disjoint across waves; gather precedes stores).
// ---------------------------------------------------------------------------
__global__ __launch_bounds__(64, 2) void heads_mfma(
    const f16* hHi,
    const int* __restrict__ idxb, const int* __restrict__ cursor,
    const f16* __restrict__ hH, const f16* __restrict__ hL,
    const float* __restrict__ hb0, const float* __restrict__ hb1,
    const float* __restrict__ hb2, const float* __restrict__ hb3,
    float* out)
{
    __shared__ f16 ACT[64 * PADK];
    const int blk = blockIdx.x;
    const int e = blk / WPE;
    const int local0 = (blk % WPE) * 64;
    const int cnt = min(cursor[e], CAP);
    const int nvalid = cnt - local0;
    if (nvalid <= 0) return;

    const int lane = threadIdx.x;
    const int l31 = lane & 31, bh = lane >> 5;

    const int myb = (lane < nvalid) ? idxb[e * CAP + local0 + lane] : -1;

    // gather: lane loads its sample's h row (256 B). Invalid rows left stale —
    // samples are independent columns in MFMA; their outputs are never stored.
    if (myb >= 0) {
        const f16* src = hHi + (size_t)myb * Hc;
#pragma unroll
        for (int j = 0; j < 16; ++j)
            *(f16x8*)(ACT + lane * PADK + j * 8) = *(const f16x8*)(src + j * 8);
    }

    const size_t we = (size_t)e * HWE_F16;
    layer64<8, true>(hH + we,         hL + we,         hb0 + e * Hc, ACT, lane);
    layer64<8, true>(hH + we + 16384, hL + we + 16384, hb1 + e * Hc, ACT, lane);
    layer64<8, true>(hH + we + 32768, hL + we + 32768, hb2 + e * Hc, ACT, lane);

    // final layer: 128 -> 64, no ReLU, direct float4 stores to out
    {
        const f16* WHi = hH + we + 49152;
        const f16* WLo = hL + we + 49152;
        const float* bias = hb3 + e * Dc;

        f16x8 af[2][8];
#pragma unroll
        for (int mt = 0; mt < 2; ++mt)
#pragma unroll
            for (int ks = 0; ks < 8; ++ks)
                af[mt][ks] = *(const f16x8*)(ACT + (32 * mt + l31) * PADK + ks * 16 + 8 * bh);

        const int bs[2] = { __shfl(myb, l31, 64), __shfl(myb, 32 + l31, 64) };

        for (int nt = 0; nt < 2; ++nt) {
            f16x8 whi[8], wlo[8];
            const f16* wp = WHi + (size_t)(32 * nt + l31) * 128 + 8 * bh;
            const f16* wq = WLo + (size_t)(32 * nt + l31) * 128 + 8 * bh;
#pragma unroll
            for (int ks = 0; ks < 8; ++ks) {
                whi[ks] = *(const f16x8*)(wp + ks * 16);
                wlo[ks] = *(const f16x8*)(wq + ks * 16);
            }
            f32x16 aH[2], aL[2];
#pragma unroll
            for (int mt = 0; mt < 2; ++mt) { aH[mt] = zero16(); aL[mt] = zero16(); }
#pragma unroll
            for (int ks = 0; ks < 8; ++ks)
#pragma unroll
                for (int mt = 0; mt < 2; ++mt) {
                    aH[mt] = MFMA(whi[ks], af[mt][ks], aH[mt]);
                    aL[mt] = MFMA(wlo[ks], af[mt][ks], aL[mt]);
                }
#pragma unroll
            for (int mt = 0; mt < 2; ++mt) {
                const int b = bs[mt];
                if (b < 0) continue;
#pragma unroll
                for (int rg = 0; rg < 4; ++rg) {
                    const int nb = 32 * nt + 8 * rg + 4 * bh;
                    const float4 bv = *(const float4*)(bias + nb);
                    float4 v;
                    v.x = fmaf(aL[mt][rg * 4 + 0], INV_LOSCALE, aH[mt][rg * 4 + 0]) + bv.x;
                    v.y = fmaf(aL[mt][rg * 4 + 1], INV_LOSCALE, aH[mt][rg * 4 + 1]) + bv.y;
                    v.z = fmaf(aL[mt][rg * 4 + 2], INV_LOSCALE, aH[mt][rg * 4 + 2]) + bv.z;
                    v.w = fmaf(aL[mt][rg * 4 + 3], INV_LOSCALE, aH[mt][rg * 4 + 3]) + bv.w;
                    *(float4*)(out + (size_t)b * Dc + nb) = v;
                }
            }
        }
    }
}

// ---------------------------------------------------------------------------
// Weight prep: split fp32 W[k][n] -> f16 hi + f16 (lo*1024), transposed to
// Wt[n][k]. One block per 32x32 tile. Block 0 also zeroes the scatter cursor.
// ---------------------------------------------------------------------------
__global__ void prep_w(
    const float* __restrict__ bw0, const float* __restrict__ bw1,
    const float* __restrict__ bw2, const float* __restrict__ bw3,
    const float* __restrict__ hw0, const float* __restrict__ hw1,
    const float* __restrict__ hw2, const float* __restrict__ hw3,
    f16* __restrict__ bbH, f16* __restrict__ bbL,
    f16* __restrict__ hH,  f16* __restrict__ hL,
    int* __restrict__ cursor)
{
    __shared__ float T[32][33];
    const int id = blockIdx.x;
    const int tx = threadIdx.x;

    if (id == 0 && tx < Kc) cursor[tx] = 0;

    const float* src; f16 *dh, *dl;
    int K, N, KD, k0, n0;

    if (id < 52) {
        if (id < 4) {
            src = bw0; dh = bbH; dl = bbL;
            K = 16; N = 128; KD = 16; k0 = 0; n0 = id * 32;
        } else {
            const int t = id - 4;
            const int l = t / 16, tile = t % 16;
            const float* bws[3] = {bw1, bw2, bw3};
            src = bws[l];
            dh = bbH + 2048 + l * 16384;
            dl = bbL + 2048 + l * 16384;
            K = 128; N = 128; KD = 128;
            k0 = (tile >> 2) * 32; n0 = (tile & 3) * 32;
        }
    } else {
        const int t = id - 52;
        const int e = t / 56, r = t % 56;
        if (r < 48) {
            const int l = r / 16, tile = r % 16;
            const float* hws[3] = {hw0, hw1, hw2};
            src = hws[l] + (size_t)e * 16384;
            dh = hH + (size_t)e * HWE_F16 + l * 16384;
            dl = hL + (size_t)e * HWE_F16 + l * 16384;
            K = 128; N = 128; KD = 128;
            k0 = (tile >> 2) * 32; n0 = (tile & 3) * 32;
        } else {
            const int r2 = r - 48;
            src = hw3 + (size_t)e * 8192;
            dh = hH + (size_t)e * HWE_F16 + 49152;
            dl = hL + (size_t)e * HWE_F16 + 49152;
            K = 128; N = 64; KD = 128;
            k0 = (r2 >> 1) * 32; n0 = (r2 & 1) * 32;
        }
    }

    const int c = tx & 31, g = tx >> 5;
#pragma unroll
    for (int i = 0; i < 4; ++i) {
        const int row = g * 4 + i;
        if (k0 + row < K)
            T[c][row] = src[(size_t)(k0 + row) * N + n0 + c];   // T[n-local][k-local]
    }
    __syncthreads();
#pragma unroll
    for (int i = 0; i < 4; ++i) {
        const int n = g * 4 + i;
        if (k0 + c < K) {
            const float v = T[n][c];
            const f16 hi = (f16)v;
            dh[(size_t)(n0 + n) * KD + k0 + c] = hi;
            dl[(size_t)(n0 + n) * KD + k0 + c] = (f16)((v - (float)hi) * 1024.0f);
        }
    }
}

// ---------------------------------------------------------------------------
extern "C" void kernel_launch(void* const* d_in, const int* in_sizes, int n_in,
                              void* d_out, int out_size, void* d_ws, size_t ws_size,
                              hipStream_t stream)
{
    const float* z   = (const float*)d_in[0];
    const int*   y   = (const int*)d_in[1];
    const float* bw0 = (const float*)d_in[2];
    const float* bb0 = (const float*)d_in[3];
    const float* bw1 = (const float*)d_in[4];
    const float* bb1 = (const float*)d_in[5];
    const float* bw2 = (const float*)d_in[6];
    const float* bb2 = (const float*)d_in[7];
    const float* bw3 = (const float*)d_in[8];
    const float* bb3 = (const float*)d_in[9];
    const float* hw0 = (const float*)d_in[10];
    const float* hb0 = (const float*)d_in[11];
    const float* hw1 = (const float*)d_in[12];
    const float* hb1 = (const float*)d_in[13];
    const float* hw2 = (const float*)d_in[14];
    const float* hb2 = (const float*)d_in[15];
    const float* hw3 = (const float*)d_in[16];
    const float* hb3 = (const float*)d_in[17];
    float* out = (float*)d_out;

    // h (f16 [B][128]) aliases d_out exactly: sample b's h row and out row
    // occupy the same 256-byte range; each heads wave gathers before storing.
    f16* hHi = (f16*)d_out;

    // workspace layout (segments 256B-aligned)
    char* p = (char*)d_ws;
    f16* bbH = (f16*)p;  p += (size_t)BBW_F16 * 2;
    f16* bbL = (f16*)p;  p += (size_t)BBW_F16 * 2;
    f16* hH  = (f16*)p;  p += (size_t)Kc * HWE_F16 * 2;
    f16* hL  = (f16*)p;  p += (size_t)Kc * HWE_F16 * 2;
    int* idxb = (int*)p; p += (size_t)Kc * CAP * 4;
    int* cursor = (int*)p;

    prep_w<<<52 + Kc * 56, 256, 0, stream>>>(bw0, bw1, bw2, bw3,
                                             hw0, hw1, hw2, hw3,
                                             bbH, bbL, hH, hL, cursor);

    backbone_mfma<<<Bc / 64, 64, 0, stream>>>(z, y, bbH, bbL,
                                              bb0, bb1, bb2, bb3,
                                              hHi, idxb, cursor);

    heads_mfma<<<NBLK, 64, 0, stream>>>(hHi, idxb, cursor,
                                        hH, hL, hb0, hb1, hb2, hb3, out);
}

// Round 5
// 196.089 us; speedup vs baseline: 1.0007x; 1.0007x over previous
//
#include <hip/hip_runtime.h>
#include <hip/hip_bf16.h>
#include <stdint.h>

// ---------------------------------------------------------------------------
// MappingNetwork: backbone 4x(Linear+ReLU) [16->128, 3x 128->128], then the
// selected expert head only (4 layers, last no-ReLU, 128->64).
//
// Round-5: ALL-REGISTER layers. Activations stay in VGPRs across all layers;
// the D-layout -> B-layout relayout between layers is done with cross-lane
// shfl_xor(32) + cndmask (no LDS anywhere in the hot path, no barriers).
//   D (operand-swapped 32x32): lane(l31,bh) reg r -> sample=l31,
//     feature(within 32-block nt) = (r&3)+8*(r>>2)+4*bh          [HW-verified]
//   B-frag: lane(l31,bh), ks: features 16ks+8bh+j, j=0..7         [HW-verified]
//   => af[2nt+k1] words: j01/j23 from lane bh=0's packed regs w[2bh_t+4k1 (+1)],
//      j45/j67 from lane bh=1's same indices — a (l, l^32) pair exchange.
//
// Numerics (validated r3/r4, absmax 1.5e-5): acts f16, W exact 2-term split
// w = whi + (wlo*1024)/1024 in separate accumulators.
// ---------------------------------------------------------------------------

typedef _Float16 f16;
typedef __attribute__((ext_vector_type(8)))  _Float16 f16x8;
typedef __attribute__((ext_vector_type(16))) float    f32x16;
typedef uint32_t u32;

#define MFMA(a, b, c) __builtin_amdgcn_mfma_f32_32x32x16_f16((a), (b), (c), 0, 0, 0)

constexpr int Bc = 65536;
constexpr int Kc = 16;     // experts
constexpr int Hc = 128;
constexpr int Dc = 64;

constexpr int CAP  = 4608;           // slots/expert = mean 4096 + 8.3 sigma
constexpr int WPE  = CAP / 64;       // 72 head waves per expert
constexpr int NBLK = Kc * WPE;       // 1152 one-wave blocks

constexpr float INV_LOSCALE = 1.0f / 1024.0f;

constexpr int BBW_F16 = 2048 + 3 * 16384;   // backbone weights (f16 elems)
constexpr int HWE_F16 = 3 * 16384 + 8192;   // per-expert head weights

union F8U { f16x8 v; u32 u[4]; };
union P2U { u32 u; f16 h[2]; };

__device__ __forceinline__ f32x16 zero16() {
    f32x16 z;
#pragma unroll
    for (int i = 0; i < 16; ++i) z[i] = 0.0f;
    return z;
}

__device__ __forceinline__ u32 pack2(float a, float b) {
    P2U x; x.h[0] = (f16)a; x.h[1] = (f16)b; return x.u;
}

// ---------------------------------------------------------------------------
// One 128-out Linear+ReLU layer, 64 samples, fully in registers.
// af: input B-frags [mt][ks]; naf: output B-frags for the next layer.
// W layout [n][KD] f16 k-fast (KD = KSTEPS*16).
// ---------------------------------------------------------------------------
template<int KSTEPS>
__device__ __forceinline__ void layer_reg(
    const f16* __restrict__ WHi, const f16* __restrict__ WLo,
    const float* __restrict__ bias,
    const f16x8 (&af)[2][8], f16x8 (&naf)[2][8], int l31, int bh)
{
    constexpr int KD = KSTEPS * 16;
#pragma unroll
    for (int nt = 0; nt < 4; ++nt) {
        f16x8 whi[KSTEPS], wlo[KSTEPS];
        const f16* wp = WHi + (size_t)(32 * nt + l31) * KD + 8 * bh;
        const f16* wq = WLo + (size_t)(32 * nt + l31) * KD + 8 * bh;
#pragma unroll
        for (int ks = 0; ks < KSTEPS; ++ks) {
            whi[ks] = *(const f16x8*)(wp + ks * 16);
            wlo[ks] = *(const f16x8*)(wq + ks * 16);
        }

        f32x16 aH[2], aL[2];
        aH[0] = zero16(); aH[1] = zero16();
        aL[0] = zero16(); aL[1] = zero16();
#pragma unroll
        for (int ks = 0; ks < KSTEPS; ++ks)
#pragma unroll
            for (int mt = 0; mt < 2; ++mt) {
                aH[mt] = MFMA(whi[ks], af[mt][ks], aH[mt]);
                aL[mt] = MFMA(wlo[ks], af[mt][ks], aL[mt]);
            }

        // epilogue: combine + bias + ReLU + pack f16x2, then pair-exchange
#pragma unroll
        for (int mt = 0; mt < 2; ++mt) {
            u32 w[8];
#pragma unroll
            for (int rg = 0; rg < 4; ++rg) {
                const float4 bv = *(const float4*)(bias + 32 * nt + 8 * rg + 4 * bh);
                float v0 = fmaf(aL[mt][4 * rg + 0], INV_LOSCALE, aH[mt][4 * rg + 0]) + bv.x;
                float v1 = fmaf(aL[mt][4 * rg + 1], INV_LOSCALE, aH[mt][4 * rg + 1]) + bv.y;
                float v2 = fmaf(aL[mt][4 * rg + 2], INV_LOSCALE, aH[mt][4 * rg + 2]) + bv.z;
                float v3 = fmaf(aL[mt][4 * rg + 3], INV_LOSCALE, aH[mt][4 * rg + 3]) + bv.w;
                v0 = fmaxf(v0, 0.0f); v1 = fmaxf(v1, 0.0f);
                v2 = fmaxf(v2, 0.0f); v3 = fmaxf(v3, 0.0f);
                w[2 * rg]     = pack2(v0, v1);
                w[2 * rg + 1] = pack2(v2, v3);
            }
            // exchange between lanes (l31, bh=0) <-> (l31, bh=1)
#pragma unroll
            for (int k1 = 0; k1 < 2; ++k1) {
                const u32 ownA = bh ? w[2 + 4 * k1] : w[0 + 4 * k1];  // w[2bh+4k1]
                const u32 ownB = bh ? w[3 + 4 * k1] : w[1 + 4 * k1];
                const u32 sA   = bh ? w[0 + 4 * k1] : w[2 + 4 * k1];  // w[2-2bh+4k1]
                const u32 sB   = bh ? w[1 + 4 * k1] : w[3 + 4 * k1];
                const u32 rA = __shfl_xor(sA, 32, 64);  // partner w[2bh+4k1]
                const u32 rB = __shfl_xor(sB, 32, 64);
                F8U o;
                o.u[0] = bh ? rA : ownA;   // j0j1
                o.u[1] = bh ? rB : ownB;   // j2j3
                o.u[2] = bh ? ownA : rA;   // j4j5
                o.u[3] = bh ? ownB : rB;   // j6j7
                naf[mt][2 * nt + k1] = o.v;
            }
        }
    }
}

// ---------------------------------------------------------------------------
// Backbone: one wave per 64 samples; z -> 4 layers (registers) -> h stored in
// B-frag layout to hHi (d_out region); fused expert scatter at the tail.
// ---------------------------------------------------------------------------
__global__ __launch_bounds__(64, 2) void backbone_mfma(
    const float* __restrict__ z, const int* __restrict__ y,
    const f16* __restrict__ bbH, const f16* __restrict__ bbL,
    const float* __restrict__ bb0, const float* __restrict__ bb1,
    const float* __restrict__ bb2, const float* __restrict__ bb3,
    f16* __restrict__ hHi, int* __restrict__ idxb, int* __restrict__ cursor)
{
    const int lane = threadIdx.x;
    const int l31 = lane & 31, bh = lane >> 5;
    const int s0 = blockIdx.x * 64;

    f16x8 af[2][8], naf[2][8];

    // z -> af[mt][0]: lane (l31,bh) holds z[s][8bh..8bh+7] as f16
#pragma unroll
    for (int mt = 0; mt < 2; ++mt) {
        const float* zp = z + (size_t)(s0 + 32 * mt + l31) * 16 + 8 * bh;
        const float4 a0 = *(const float4*)(zp);
        const float4 a1 = *(const float4*)(zp + 4);
        f16x8 t;
        t[0] = (f16)a0.x; t[1] = (f16)a0.y; t[2] = (f16)a0.z; t[3] = (f16)a0.w;
        t[4] = (f16)a1.x; t[5] = (f16)a1.y; t[6] = (f16)a1.z; t[7] = (f16)a1.w;
        af[mt][0] = t;
    }

    layer_reg<1>(bbH,         bbL,         bb0, af,  naf, l31, bh);
    layer_reg<8>(bbH + 2048,  bbL + 2048,  bb1, naf, af,  l31, bh);
    layer_reg<8>(bbH + 18432, bbL + 18432, bb2, af,  naf, l31, bh);
    layer_reg<8>(bbH + 34816, bbL + 34816, bb3, naf, af,  l31, bh);

    // store h in B-frag layout: hHi[b*128 + 16ks + 8bh .. +7] = af[mt][ks]
#pragma unroll
    for (int mt = 0; mt < 2; ++mt) {
        f16* hp = hHi + (size_t)(s0 + 32 * mt + l31) * Hc + 8 * bh;
#pragma unroll
        for (int ks = 0; ks < 8; ++ks)
            *(f16x8*)(hp + ks * 16) = af[mt][ks];
    }

    // fused scatter (tiny LDS, end of kernel, 1-wave block)
    __shared__ int lc[Kc];
    __shared__ int lbase[Kc];
    if (lane < Kc) lc[lane] = 0;
    __syncthreads();
    const int e = y[s0 + lane];
    const int r = atomicAdd(&lc[e], 1);
    __syncthreads();
    if (lane < Kc) lbase[lane] = atomicAdd(&cursor[lane], lc[lane]);
    __syncthreads();
    const int slot = lbase[e] + r;
    if (slot < CAP) idxb[e * CAP + slot] = s0 + lane;
}

// ---------------------------------------------------------------------------
// Heads: one wave per 64 samples of one expert, all in registers.
// Gather h B-frags directly (b128 loads), 3 reg-layers, final 128->64 with
// direct float4 stores to out[b]. hHi aliases d_out (row-disjoint, read-first).
// ---------------------------------------------------------------------------
__global__ __launch_bounds__(64, 2) void heads_mfma(
    const f16* hHi,
    const int* __restrict__ idxb, const int* __restrict__ cursor,
    const f16* __restrict__ hH, const f16* __restrict__ hL,
    const float* __restrict__ hb0, const float* __restrict__ hb1,
    const float* __restrict__ hb2, const float* __restrict__ hb3,
    float* out)
{
    const int blk = blockIdx.x;
    const int e = blk / WPE;
    const int local0 = (blk % WPE) * 64;
    const int cnt = min(cursor[e], CAP);
    const int nvalid = cnt - local0;
    if (nvalid <= 0) return;

    const int lane = threadIdx.x;
    const int l31 = lane & 31, bh = lane >> 5;

    f16x8 af[2][8], naf[2][8];
    int myb[2];
#pragma unroll
    for (int mt = 0; mt < 2; ++mt) {
        const int li = 32 * mt + l31;
        myb[mt] = (li < nvalid) ? idxb[e * CAP + local0 + li] : -1;
        if (myb[mt] >= 0) {
            const f16* hp = hHi + (size_t)myb[mt] * Hc + 8 * bh;
#pragma unroll
            for (int ks = 0; ks < 8; ++ks)
                af[mt][ks] = *(const f16x8*)(hp + ks * 16);
        } else {
            f16x8 zz;
#pragma unroll
            for (int j = 0; j < 8; ++j) zz[j] = (f16)0.0f;
#pragma unroll
            for (int ks = 0; ks < 8; ++ks) af[mt][ks] = zz;
        }
    }

    const size_t we = (size_t)e * HWE_F16;
    layer_reg<8>(hH + we,         hL + we,         hb0 + e * Hc, af,  naf, l31, bh);
    layer_reg<8>(hH + we + 16384, hL + we + 16384, hb1 + e * Hc, naf, af,  l31, bh);
    layer_reg<8>(hH + we + 32768, hL + we + 32768, hb2 + e * Hc, af,  naf, l31, bh);

    // final layer: 128 -> 64, no ReLU, direct float4 stores
    {
        const f16* WHi = hH + we + 49152;
        const f16* WLo = hL + we + 49152;
        const float* bias = hb3 + e * Dc;
#pragma unroll
        for (int nt = 0; nt < 2; ++nt) {
            f16x8 whi[8], wlo[8];
            const f16* wp = WHi + (size_t)(32 * nt + l31) * 128 + 8 * bh;
            const f16* wq = WLo + (size_t)(32 * nt + l31) * 128 + 8 * bh;
#pragma unroll
            for (int ks = 0; ks < 8; ++ks) {
                whi[ks] = *(const f16x8*)(wp + ks * 16);
                wlo[ks] = *(const f16x8*)(wq + ks * 16);
            }
            f32x16 aH[2], aL[2];
            aH[0] = zero16(); aH[1] = zero16();
            aL[0] = zero16(); aL[1] = zero16();
#pragma unroll
            for (int ks = 0; ks < 8; ++ks)
#pragma unroll
                for (int mt = 0; mt < 2; ++mt) {
                    aH[mt] = MFMA(whi[ks], naf[mt][ks], aH[mt]);
                    aL[mt] = MFMA(wlo[ks], naf[mt][ks], aL[mt]);
                }
#pragma unroll
            for (int mt = 0; mt < 2; ++mt) {
                const int b = myb[mt];
                if (b < 0) continue;
#pragma unroll
                for (int rg = 0; rg < 4; ++rg) {
                    const int nb = 32 * nt + 8 * rg + 4 * bh;
                    const float4 bv = *(const float4*)(bias + nb);
                    float4 v;
                    v.x = fmaf(aL[mt][rg * 4 + 0], INV_LOSCALE, aH[mt][rg * 4 + 0]) + bv.x;
                    v.y = fmaf(aL[mt][rg * 4 + 1], INV_LOSCALE, aH[mt][rg * 4 + 1]) + bv.y;
                    v.z = fmaf(aL[mt][rg * 4 + 2], INV_LOSCALE, aH[mt][rg * 4 + 2]) + bv.z;
                    v.w = fmaf(aL[mt][rg * 4 + 3], INV_LOSCALE, aH[mt][rg * 4 + 3]) + bv.w;
                    *(float4*)(out + (size_t)b * Dc + nb) = v;
                }
            }
        }
    }
}

// ---------------------------------------------------------------------------
// Weight prep: split fp32 W[k][n] -> f16 hi + f16 (lo*1024), transposed to
// Wt[n][k]. One block per 32x32 tile. Block 0 also zeroes the scatter cursor.
// ---------------------------------------------------------------------------
__global__ void prep_w(
    const float* __restrict__ bw0, const float* __restrict__ bw1,
    const float* __restrict__ bw2, const float* __restrict__ bw3,
    const float* __restrict__ hw0, const float* __restrict__ hw1,
    const float* __restrict__ hw2, const float* __restrict__ hw3,
    f16* __restrict__ bbH, f16* __restrict__ bbL,
    f16* __restrict__ hH,  f16* __restrict__ hL,
    int* __restrict__ cursor)
{
    __shared__ float T[32][33];
    const int id = blockIdx.x;
    const int tx = threadIdx.x;

    if (id == 0 && tx < Kc) cursor[tx] = 0;

    const float* src; f16 *dh, *dl;
    int K, N, KD, k0, n0;

    if (id < 52) {
        if (id < 4) {
            src = bw0; dh = bbH; dl = bbL;
            K = 16; N = 128; KD = 16; k0 = 0; n0 = id * 32;
        } else {
            const int t = id - 4;
            const int l = t / 16, tile = t % 16;
            const float* bws[3] = {bw1, bw2, bw3};
            src = bws[l];
            dh = bbH + 2048 + l * 16384;
            dl = bbL + 2048 + l * 16384;
            K = 128; N = 128; KD = 128;
            k0 = (tile >> 2) * 32; n0 = (tile & 3) * 32;
        }
    } else {
        const int t = id - 52;
        const int e = t / 56, r = t % 56;
        if (r < 48) {
            const int l = r / 16, tile = r % 16;
            const float* hws[3] = {hw0, hw1, hw2};
            src = hws[l] + (size_t)e * 16384;
            dh = hH + (size_t)e * HWE_F16 + l * 16384;
            dl = hL + (size_t)e * HWE_F16 + l * 16384;
            K = 128; N = 128; KD = 128;
            k0 = (tile >> 2) * 32; n0 = (tile & 3) * 32;
        } else {
            const int r2 = r - 48;
            src = hw3 + (size_t)e * 8192;
            dh = hH + (size_t)e * HWE_F16 + 49152;
            dl = hL + (size_t)e * HWE_F16 + 49152;
            K = 128; N = 64; KD = 128;
            k0 = (r2 >> 1) * 32; n0 = (r2 & 1) * 32;
        }
    }

    const int c = tx & 31, g = tx >> 5;
#pragma unroll
    for (int i = 0; i < 4; ++i) {
        const int row = g * 4 + i;
        if (k0 + row < K)
            T[c][row] = src[(size_t)(k0 + row) * N + n0 + c];   // T[n-local][k-local]
    }
    __syncthreads();
#pragma unroll
    for (int i = 0; i < 4; ++i) {
        const int n = g * 4 + i;
        if (k0 + c < K) {
            const float v = T[n][c];
            const f16 hi = (f16)v;
            dh[(size_t)(n0 + n) * KD + k0 + c] = hi;
            dl[(size_t)(n0 + n) * KD + k0 + c] = (f16)((v - (float)hi) * 1024.0f);
        }
    }
}

// ---------------------------------------------------------------------------
extern "C" void kernel_launch(void* const* d_in, const int* in_sizes, int n_in,
                              void* d_out, int out_size, void* d_ws, size_t ws_size,
                              hipStream_t stream)
{
    const float* z   = (const float*)d_in[0];
    const int*   y   = (const int*)d_in[1];
    const float* bw0 = (const float*)d_in[2];
    const float* bb0 = (const float*)d_in[3];
    const float* bw1 = (const float*)d_in[4];
    const float* bb1 = (const float*)d_in[5];
    const float* bw2 = (const float*)d_in[6];
    const float* bb2 = (const float*)d_in[7];
    const float* bw3 = (const float*)d_in[8];
    const float* bb3 = (const float*)d_in[9];
    const float* hw0 = (const float*)d_in[10];
    const float* hb0 = (const float*)d_in[11];
    const float* hw1 = (const float*)d_in[12];
    const float* hb1 = (const float*)d_in[13];
    const float* hw2 = (const float*)d_in[14];
    const float* hb2 = (const float*)d_in[15];
    const float* hw3 = (const float*)d_in[16];
    const float* hb3 = (const float*)d_in[17];
    float* out = (float*)d_out;

    // h (f16 [B][128], B-frag layout) aliases d_out exactly: sample b's h row
    // and out row occupy the same 256-byte range; gather precedes store.
    f16* hHi = (f16*)d_out;

    // workspace layout (segments 256B-aligned)
    char* p = (char*)d_ws;
    f16* bbH = (f16*)p;  p += (size_t)BBW_F16 * 2;
    f16* bbL = (f16*)p;  p += (size_t)BBW_F16 * 2;
    f16* hH  = (f16*)p;  p += (size_t)Kc * HWE_F16 * 2;
    f16* hL  = (f16*)p;  p += (size_t)Kc * HWE_F16 * 2;
    int* idxb = (int*)p; p += (size_t)Kc * CAP * 4;
    int* cursor = (int*)p;

    prep_w<<<52 + Kc * 56, 256, 0, stream>>>(bw0, bw1, bw2, bw3,
                                             hw0, hw1, hw2, hw3,
                                             bbH, bbL, hH, hL, cursor);

    backbone_mfma<<<Bc / 64, 64, 0, stream>>>(z, y, bbH, bbL,
                                              bb0, bb1, bb2, bb3,
                                              hHi, idxb, cursor);

    heads_mfma<<<NBLK, 64, 0, stream>>>(hHi, idxb, cursor,
                                        hH, hL, hb0, hb1, hb2, hb3, out);
}

// Round 6
// 187.610 us; speedup vs baseline: 1.0459x; 1.0452x over previous
//
#include <hip/hip_runtime.h>
#include <hip/hip_bf16.h>
#include <stdint.h>

// ---------------------------------------------------------------------------
// MappingNetwork: backbone 4x(Linear+ReLU) [16->128, 3x 128->128], then the
// selected expert head only (4 layers, last no-ReLU, 128->64).
//
// Round-6: r5's all-register structure + REGISTER-BUDGET FIX.
//   * __launch_bounds__(64,1): VGPR cap 512 — the r2-r5 flatline at ~60 us
//     per kernel was the compiler capping VGPRs (88-128) below the ~280-reg
//     live set and spilling/rematerializing every nt iteration at exposed
//     L2 latency (~1 wave/SIMD). Grid is 4 one-wave blocks/CU regardless,
//     so raising the cap costs no occupancy.
//   * Manual W double-buffer across the nt loop: prefetch nt+1's W frags
//     during nt's MFMA+epilogue (hides L2 latency at 1 wave/SIMD).
//
// Numerics (validated r3-r5, absmax 1.5259e-5): acts f16, W exact 2-term
// split w = whi + (wlo*1024)/1024 in separate accumulators.
// Layout transform between layers: shfl_xor(32) pair exchange (HW-verified
// via r4/r5 passing). No LDS, no barriers on the hot path.
// ---------------------------------------------------------------------------

typedef _Float16 f16;
typedef __attribute__((ext_vector_type(8)))  _Float16 f16x8;
typedef __attribute__((ext_vector_type(16))) float    f32x16;
typedef uint32_t u32;

#define MFMA(a, b, c) __builtin_amdgcn_mfma_f32_32x32x16_f16((a), (b), (c), 0, 0, 0)

constexpr int Bc = 65536;
constexpr int Kc = 16;     // experts
constexpr int Hc = 128;
constexpr int Dc = 64;

constexpr int CAP  = 4608;           // slots/expert = mean 4096 + 8.3 sigma
constexpr int WPE  = CAP / 64;       // 72 head waves per expert
constexpr int NBLK = Kc * WPE;       // 1152 one-wave blocks

constexpr float INV_LOSCALE = 1.0f / 1024.0f;

constexpr int BBW_F16 = 2048 + 3 * 16384;   // backbone weights (f16 elems)
constexpr int HWE_F16 = 3 * 16384 + 8192;   // per-expert head weights

union F8U { f16x8 v; u32 u[4]; };
union P2U { u32 u; f16 h[2]; };

__device__ __forceinline__ f32x16 zero16() {
    f32x16 z;
#pragma unroll
    for (int i = 0; i < 16; ++i) z[i] = 0.0f;
    return z;
}

__device__ __forceinline__ u32 pack2(float a, float b) {
    P2U x; x.h[0] = (f16)a; x.h[1] = (f16)b; return x.u;
}

// ---------------------------------------------------------------------------
// One 128-out Linear+ReLU layer, 64 samples, fully in registers.
// af: input B-frags [mt][ks]; naf: output B-frags for the next layer.
// W layout [n][KD] f16 k-fast (KD = KSTEPS*16). W is double-buffered across
// the nt loop: nt+1's 16 frags are in flight while nt computes.
// ---------------------------------------------------------------------------
template<int KSTEPS>
__device__ __forceinline__ void layer_reg(
    const f16* __restrict__ WHi, const f16* __restrict__ WLo,
    const float* __restrict__ bias,
    const f16x8 (&af)[2][8], f16x8 (&naf)[2][8], int l31, int bh)
{
    constexpr int KD = KSTEPS * 16;
    const f16* wpb = WHi + (size_t)l31 * KD + 8 * bh;   // row l31, +32-row steps per nt
    const f16* wqb = WLo + (size_t)l31 * KD + 8 * bh;

    f16x8 whi[2][KSTEPS], wlo[2][KSTEPS];
#pragma unroll
    for (int ks = 0; ks < KSTEPS; ++ks) {
        whi[0][ks] = *(const f16x8*)(wpb + ks * 16);
        wlo[0][ks] = *(const f16x8*)(wqb + ks * 16);
    }

#pragma unroll
    for (int nt = 0; nt < 4; ++nt) {
        const int cur = nt & 1, nxt = cur ^ 1;
        // prefetch nt+1's W while nt computes
        if (nt < 3) {
            const size_t roff = (size_t)(nt + 1) * 32 * KD;
#pragma unroll
            for (int ks = 0; ks < KSTEPS; ++ks) {
                whi[nxt][ks] = *(const f16x8*)(wpb + roff + ks * 16);
                wlo[nxt][ks] = *(const f16x8*)(wqb + roff + ks * 16);
            }
        }

        f32x16 aH[2], aL[2];
        aH[0] = zero16(); aH[1] = zero16();
        aL[0] = zero16(); aL[1] = zero16();
#pragma unroll
        for (int ks = 0; ks < KSTEPS; ++ks)
#pragma unroll
            for (int mt = 0; mt < 2; ++mt) {
                aH[mt] = MFMA(whi[cur][ks], af[mt][ks], aH[mt]);
                aL[mt] = MFMA(wlo[cur][ks], af[mt][ks], aL[mt]);
            }

        // epilogue: combine + bias + ReLU + pack f16x2, then pair-exchange
#pragma unroll
        for (int mt = 0; mt < 2; ++mt) {
            u32 w[8];
#pragma unroll
            for (int rg = 0; rg < 4; ++rg) {
                const float4 bv = *(const float4*)(bias + 32 * nt + 8 * rg + 4 * bh);
                float v0 = fmaf(aL[mt][4 * rg + 0], INV_LOSCALE, aH[mt][4 * rg + 0]) + bv.x;
                float v1 = fmaf(aL[mt][4 * rg + 1], INV_LOSCALE, aH[mt][4 * rg + 1]) + bv.y;
                float v2 = fmaf(aL[mt][4 * rg + 2], INV_LOSCALE, aH[mt][4 * rg + 2]) + bv.z;
                float v3 = fmaf(aL[mt][4 * rg + 3], INV_LOSCALE, aH[mt][4 * rg + 3]) + bv.w;
                v0 = fmaxf(v0, 0.0f); v1 = fmaxf(v1, 0.0f);
                v2 = fmaxf(v2, 0.0f); v3 = fmaxf(v3, 0.0f);
                w[2 * rg]     = pack2(v0, v1);
                w[2 * rg + 1] = pack2(v2, v3);
            }
            // exchange between lanes (l31, bh=0) <-> (l31, bh=1)
#pragma unroll
            for (int k1 = 0; k1 < 2; ++k1) {
                const u32 ownA = bh ? w[2 + 4 * k1] : w[0 + 4 * k1];
                const u32 ownB = bh ? w[3 + 4 * k1] : w[1 + 4 * k1];
                const u32 sA   = bh ? w[0 + 4 * k1] : w[2 + 4 * k1];
                const u32 sB   = bh ? w[1 + 4 * k1] : w[3 + 4 * k1];
                const u32 rA = __shfl_xor(sA, 32, 64);
                const u32 rB = __shfl_xor(sB, 32, 64);
                F8U o;
                o.u[0] = bh ? rA : ownA;
                o.u[1] = bh ? rB : ownB;
                o.u[2] = bh ? ownA : rA;
                o.u[3] = bh ? ownB : rB;
                naf[mt][2 * nt + k1] = o.v;
            }
        }
    }
}

// ---------------------------------------------------------------------------
// Backbone: one wave per 64 samples; z -> 4 layers (registers) -> h stored in
// B-frag layout to hHi (d_out region); fused expert scatter at the tail.
// ---------------------------------------------------------------------------
__global__ __launch_bounds__(64, 1) void backbone_mfma(
    const float* __restrict__ z, const int* __restrict__ y,
    const f16* __restrict__ bbH, const f16* __restrict__ bbL,
    const float* __restrict__ bb0, const float* __restrict__ bb1,
    const float* __restrict__ bb2, const float* __restrict__ bb3,
    f16* __restrict__ hHi, int* __restrict__ idxb, int* __restrict__ cursor)
{
    const int lane = threadIdx.x;
    const int l31 = lane & 31, bh = lane >> 5;
    const int s0 = blockIdx.x * 64;

    f16x8 af[2][8], naf[2][8];

    // z -> af[mt][0]: lane (l31,bh) holds z[s][8bh..8bh+7] as f16
#pragma unroll
    for (int mt = 0; mt < 2; ++mt) {
        const float* zp = z + (size_t)(s0 + 32 * mt + l31) * 16 + 8 * bh;
        const float4 a0 = *(const float4*)(zp);
        const float4 a1 = *(const float4*)(zp + 4);
        f16x8 t;
        t[0] = (f16)a0.x; t[1] = (f16)a0.y; t[2] = (f16)a0.z; t[3] = (f16)a0.w;
        t[4] = (f16)a1.x; t[5] = (f16)a1.y; t[6] = (f16)a1.z; t[7] = (f16)a1.w;
        af[mt][0] = t;
    }

    layer_reg<1>(bbH,         bbL,         bb0, af,  naf, l31, bh);
    layer_reg<8>(bbH + 2048,  bbL + 2048,  bb1, naf, af,  l31, bh);
    layer_reg<8>(bbH + 18432, bbL + 18432, bb2, af,  naf, l31, bh);
    layer_reg<8>(bbH + 34816, bbL + 34816, bb3, naf, af,  l31, bh);

    // store h in B-frag layout: hHi[b*128 + 16ks + 8bh .. +7] = af[mt][ks]
#pragma unroll
    for (int mt = 0; mt < 2; ++mt) {
        f16* hp = hHi + (size_t)(s0 + 32 * mt + l31) * Hc + 8 * bh;
#pragma unroll
        for (int ks = 0; ks < 8; ++ks)
            *(f16x8*)(hp + ks * 16) = af[mt][ks];
    }

    // fused scatter (tiny LDS, end of kernel, 1-wave block)
    __shared__ int lc[Kc];
    __shared__ int lbase[Kc];
    if (lane < Kc) lc[lane] = 0;
    __syncthreads();
    const int e = y[s0 + lane];
    const int r = atomicAdd(&lc[e], 1);
    __syncthreads();
    if (lane < Kc) lbase[lane] = atomicAdd(&cursor[lane], lc[lane]);
    __syncthreads();
    const int slot = lbase[e] + r;
    if (slot < CAP) idxb[e * CAP + slot] = s0 + lane;
}

// ---------------------------------------------------------------------------
// Heads: one wave per 64 samples of one expert, all in registers.
// Gather h B-frags directly (b128 loads), 3 reg-layers, final 128->64 with
// direct float4 stores to out[b]. hHi aliases d_out (row-disjoint, read-first).
// ---------------------------------------------------------------------------
__global__ __launch_bounds__(64, 1) void heads_mfma(
    const f16* hHi,
    const int* __restrict__ idxb, const int* __restrict__ cursor,
    const f16* __restrict__ hH, const f16* __restrict__ hL,
    const float* __restrict__ hb0, const float* __restrict__ hb1,
    const float* __restrict__ hb2, const float* __restrict__ hb3,
    float* out)
{
    const int blk = blockIdx.x;
    const int e = blk / WPE;
    const int local0 = (blk % WPE) * 64;
    const int cnt = min(cursor[e], CAP);
    const int nvalid = cnt - local0;
    if (nvalid <= 0) return;

    const int lane = threadIdx.x;
    const int l31 = lane & 31, bh = lane >> 5;

    f16x8 af[2][8], naf[2][8];
    int myb[2];
#pragma unroll
    for (int mt = 0; mt < 2; ++mt) {
        const int li = 32 * mt + l31;
        myb[mt] = (li < nvalid) ? idxb[e * CAP + local0 + li] : -1;
        if (myb[mt] >= 0) {
            const f16* hp = hHi + (size_t)myb[mt] * Hc + 8 * bh;
#pragma unroll
            for (int ks = 0; ks < 8; ++ks)
                af[mt][ks] = *(const f16x8*)(hp + ks * 16);
        } else {
            f16x8 zz;
#pragma unroll
            for (int j = 0; j < 8; ++j) zz[j] = (f16)0.0f;
#pragma unroll
            for (int ks = 0; ks < 8; ++ks) af[mt][ks] = zz;
        }
    }

    const size_t we = (size_t)e * HWE_F16;
    layer_reg<8>(hH + we,         hL + we,         hb0 + e * Hc, af,  naf, l31, bh);
    layer_reg<8>(hH + we + 16384, hL + we + 16384, hb1 + e * Hc, naf, af,  l31, bh);
    layer_reg<8>(hH + we + 32768, hL + we + 32768, hb2 + e * Hc, af,  naf, l31, bh);

    // final layer: 128 -> 64, no ReLU, W double-buffered, float4 stores
    {
        const f16* wpb = hH + we + 49152 + (size_t)l31 * 128 + 8 * bh;
        const f16* wqb = hL + we + 49152 + (size_t)l31 * 128 + 8 * bh;
        const float* bias = hb3 + e * Dc;

        f16x8 whi[2][8], wlo[2][8];
#pragma unroll
        for (int ks = 0; ks < 8; ++ks) {
            whi[0][ks] = *(const f16x8*)(wpb + ks * 16);
            wlo[0][ks] = *(const f16x8*)(wqb + ks * 16);
        }

#pragma unroll
        for (int nt = 0; nt < 2; ++nt) {
            const int cur = nt & 1, nxt = cur ^ 1;
            if (nt < 1) {
#pragma unroll
                for (int ks = 0; ks < 8; ++ks) {
                    whi[nxt][ks] = *(const f16x8*)(wpb + (size_t)32 * 128 + ks * 16);
                    wlo[nxt][ks] = *(const f16x8*)(wqb + (size_t)32 * 128 + ks * 16);
                }
            }
            f32x16 aH[2], aL[2];
            aH[0] = zero16(); aH[1] = zero16();
            aL[0] = zero16(); aL[1] = zero16();
#pragma unroll
            for (int ks = 0; ks < 8; ++ks)
#pragma unroll
                for (int mt = 0; mt < 2; ++mt) {
                    aH[mt] = MFMA(whi[cur][ks], naf[mt][ks], aH[mt]);
                    aL[mt] = MFMA(wlo[cur][ks], naf[mt][ks], aL[mt]);
                }
#pragma unroll
            for (int mt = 0; mt < 2; ++mt) {
                const int b = myb[mt];
                if (b < 0) continue;
#pragma unroll
                for (int rg = 0; rg < 4; ++rg) {
                    const int nb = 32 * nt + 8 * rg + 4 * bh;
                    const float4 bv = *(const float4*)(bias + nb);
                    float4 v;
                    v.x = fmaf(aL[mt][rg * 4 + 0], INV_LOSCALE, aH[mt][rg * 4 + 0]) + bv.x;
                    v.y = fmaf(aL[mt][rg * 4 + 1], INV_LOSCALE, aH[mt][rg * 4 + 1]) + bv.y;
                    v.z = fmaf(aL[mt][rg * 4 + 2], INV_LOSCALE, aH[mt][rg * 4 + 2]) + bv.z;
                    v.w = fmaf(aL[mt][rg * 4 + 3], INV_LOSCALE, aH[mt][rg * 4 + 3]) + bv.w;
                    *(float4*)(out + (size_t)b * Dc + nb) = v;
                }
            }
        }
    }
}

// ---------------------------------------------------------------------------
// Weight prep: split fp32 W[k][n] -> f16 hi + f16 (lo*1024), transposed to
// Wt[n][k]. One block per 32x32 tile. Block 0 also zeroes the scatter cursor.
// ---------------------------------------------------------------------------
__global__ void prep_w(
    const float* __restrict__ bw0, const float* __restrict__ bw1,
    const float* __restrict__ bw2, const float* __restrict__ bw3,
    const float* __restrict__ hw0, const float* __restrict__ hw1,
    const float* __restrict__ hw2, const float* __restrict__ hw3,
    f16* __restrict__ bbH, f16* __restrict__ bbL,
    f16* __restrict__ hH,  f16* __restrict__ hL,
    int* __restrict__ cursor)
{
    __shared__ float T[32][33];
    const int id = blockIdx.x;
    const int tx = threadIdx.x;

    if (id == 0 && tx < Kc) cursor[tx] = 0;

    const float* src; f16 *dh, *dl;
    int K, N, KD, k0, n0;

    if (id < 52) {
        if (id < 4) {
            src = bw0; dh = bbH; dl = bbL;
            K = 16; N = 128; KD = 16; k0 = 0; n0 = id * 32;
        } else {
            const int t = id - 4;
            const int l = t / 16, tile = t % 16;
            const float* bws[3] = {bw1, bw2, bw3};
            src = bws[l];
            dh = bbH + 2048 + l * 16384;
            dl = bbL + 2048 + l * 16384;
            K = 128; N = 128; KD = 128;
            k0 = (tile >> 2) * 32; n0 = (tile & 3) * 32;
        }
    } else {
        const int t = id - 52;
        const int e = t / 56, r = t % 56;
        if (r < 48) {
            const int l = r / 16, tile = r % 16;
            const float* hws[3] = {hw0, hw1, hw2};
            src = hws[l] + (size_t)e * 16384;
            dh = hH + (size_t)e * HWE_F16 + l * 16384;
            dl = hL + (size_t)e * HWE_F16 + l * 16384;
            K = 128; N = 128; KD = 128;
            k0 = (tile >> 2) * 32; n0 = (tile & 3) * 32;
        } else {
            const int r2 = r - 48;
            src = hw3 + (size_t)e * 8192;
            dh = hH + (size_t)e * HWE_F16 + 49152;
            dl = hL + (size_t)e * HWE_F16 + 49152;
            K = 128; N = 64; KD = 128;
            k0 = (r2 >> 1) * 32; n0 = (r2 & 1) * 32;
        }
    }

    const int c = tx & 31, g = tx >> 5;
#pragma unroll
    for (int i = 0; i < 4; ++i) {
        const int row = g * 4 + i;
        if (k0 + row < K)
            T[c][row] = src[(size_t)(k0 + row) * N + n0 + c];   // T[n-local][k-local]
    }
    __syncthreads();
#pragma unroll
    for (int i = 0; i < 4; ++i) {
        const int n = g * 4 + i;
        if (k0 + c < K) {
            const float v = T[n][c];
            const f16 hi = (f16)v;
            dh[(size_t)(n0 + n) * KD + k0 + c] = hi;
            dl[(size_t)(n0 + n) * KD + k0 + c] = (f16)((v - (float)hi) * 1024.0f);
        }
    }
}

// ---------------------------------------------------------------------------
extern "C" void kernel_launch(void* const* d_in, const int* in_sizes, int n_in,
                              void* d_out, int out_size, void* d_ws, size_t ws_size,
                              hipStream_t stream)
{
    const float* z   = (const float*)d_in[0];
    const int*   y   = (const int*)d_in[1];
    const float* bw0 = (const float*)d_in[2];
    const float* bb0 = (const float*)d_in[3];
    const float* bw1 = (const float*)d_in[4];
    const float* bb1 = (const float*)d_in[5];
    const float* bw2 = (const float*)d_in[6];
    const float* bb2 = (const float*)d_in[7];
    const float* bw3 = (const float*)d_in[8];
    const float* bb3 = (const float*)d_in[9];
    const float* hw0 = (const float*)d_in[10];
    const float* hb0 = (const float*)d_in[11];
    const float* hw1 = (const float*)d_in[12];
    const float* hb1 = (const float*)d_in[13];
    const float* hw2 = (const float*)d_in[14];
    const float* hb2 = (const float*)d_in[15];
    const float* hw3 = (const float*)d_in[16];
    const float* hb3 = (const float*)d_in[17];
    float* out = (float*)d_out;

    // h (f16 [B][128], B-frag layout) aliases d_out exactly: sample b's h row
    // and out row occupy the same 256-byte range; gather precedes store.
    f16* hHi = (f16*)d_out;

    // workspace layout (segments 256B-aligned)
    char* p = (char*)d_ws;
    f16* bbH = (f16*)p;  p += (size_t)BBW_F16 * 2;
    f16* bbL = (f16*)p;  p += (size_t)BBW_F16 * 2;
    f16* hH  = (f16*)p;  p += (size_t)Kc * HWE_F16 * 2;
    f16* hL  = (f16*)p;  p += (size_t)Kc * HWE_F16 * 2;
    int* idxb = (int*)p; p += (size_t)Kc * CAP * 4;
    int* cursor = (int*)p;

    prep_w<<<52 + Kc * 56, 256, 0, stream>>>(bw0, bw1, bw2, bw3,
                                             hw0, hw1, hw2, hw3,
                                             bbH, bbL, hH, hL, cursor);

    backbone_mfma<<<Bc / 64, 64, 0, stream>>>(z, y, bbH, bbL,
                                              bb0, bb1, bb2, bb3,
                                              hHi, idxb, cursor);

    heads_mfma<<<NBLK, 64, 0, stream>>>(hHi, idxb, cursor,
                                        hH, hL, hb0, hb1, hb2, hb3, out);
}